// Round 1
// baseline (185.693 us; speedup 1.0000x reference)
//
#include <hip/hip_runtime.h>

// x: (128, 32, 2, 64, 64) f32.  out: (128, 32) f32.
// plaq[b,h,i,j] = t0[i][j] + t1[(i+1)%64][j] - t0[i][(j+1)%64] - t1[i][j]
// out[b,h] = mean_{i,j} cos(plaq)
//
// Register-pipelined t1 version: each wave owns HALF of one (b,h) image
// (32 rows).  Lane L: dr = L>>4 selects an 8-consecutive-row strip
// (rows 32*half + 8*dr .. +7), c = L&15 selects cols 4c..4c+3.
// Per iteration k the lane loads t0[r] and t1[r+1]; t1[r] is carried in
// a register from the previous iteration (preloaded for k=0).  Every t1
// row is therefore fetched from HBM exactly once (the 4 strip-boundary
// rows per half are re-read a whole loop later -> L2 hit), eliminating
// the concurrent duplicate t1 fetch of the previous version (~1.5x
// HBM traffic -> ~1.06x).  VMEM instr count drops ~29%.
// Col-neighbor t0[i][j+1]: in-register (.y/.z/.w) except the float4
// boundary, which is one ds_bpermute of the next col-group's .x
// (all lanes of a dr-group sit on the same row, so same-iteration
// shfl is exact, with c=15 wrapping to c=0).

__global__ __launch_bounds__(256) void plaq_mean_cos_kernel(
    const float* __restrict__ x, float* __restrict__ out) {
    const int t    = threadIdx.x;
    const int lane = t & 63;
    const int w    = t >> 6;        // wave 0..3
    const int half = w & 1;         // which 32-row half of the image
    const int p    = w >> 1;        // which (b,h) of this block
    const int dr   = lane >> 4;     // 8-row strip within the half
    const int c    = lane & 15;     // col group: cols 4c..4c+3

    const int bh = blockIdx.x * 2 + p;
    const float* __restrict__ base = x + (size_t)bh * 8192;  // [2][64][64]
    const float* __restrict__ t0p  = base;
    const float* __restrict__ t1p  = base + 4096;

    const int r0 = (half << 5) + (dr << 3);  // first row of this lane's strip
    const int co = c << 2;                   // first col

    // lane holding the next col-group's t0 .x (same dr-group, same row)
    const int nlane = (lane & 48) | ((c + 1) & 15);

    // preload t1[r0]
    float4 t1c = *(const float4*)&t1p[(r0 << 6) + co];

    float sum = 0.0f;
    #pragma unroll
    for (int k = 0; k < 8; ++k) {
        const int r  = r0 + k;
        const int rn = (r + 1) & 63;                      // row neighbor (wraps)
        const float4 t0v = *(const float4*)&t0p[(r << 6) + co];
        const float4 t1n = *(const float4*)&t1p[(rn << 6) + co];
        const float  nx  = __shfl(t0v.x, nlane, 64);      // t0[r][4(c+1) mod 64]

        sum += __cosf(t0v.x + t1n.x - t0v.y - t1c.x);
        sum += __cosf(t0v.y + t1n.y - t0v.z - t1c.y);
        sum += __cosf(t0v.z + t1n.z - t0v.w - t1c.z);
        sum += __cosf(t0v.w + t1n.w - nx    - t1c.w);

        t1c = t1n;   // register pipeline: t1[r+1] becomes next iter's t1[r]
    }

    // Wave (64-lane) butterfly reduce.
    #pragma unroll
    for (int off = 32; off > 0; off >>= 1)
        sum += __shfl_down(sum, off, 64);

    __shared__ float wsum[4];
    if (lane == 0) wsum[w] = sum;
    __syncthreads();
    // waves 0,1 -> bh = blockIdx.x*2 ; waves 2,3 -> blockIdx.x*2+1
    if (t == 0)   out[bh] = (wsum[0] + wsum[1]) * (1.0f / 4096.0f);
    if (t == 128) out[bh] = (wsum[2] + wsum[3]) * (1.0f / 4096.0f);
}

extern "C" void kernel_launch(void* const* d_in, const int* in_sizes, int n_in,
                              void* d_out, int out_size, void* d_ws, size_t ws_size,
                              hipStream_t stream) {
    const float* x = (const float*)d_in[0];
    float* out = (float*)d_out;
    plaq_mean_cos_kernel<<<2048, 256, 0, stream>>>(x, out);
}

// Round 2
// 182.275 us; speedup vs baseline: 1.0188x; 1.0188x over previous
//
#include <hip/hip_runtime.h>

// x: (128, 32, 2, 64, 64) f32.  out: (128, 32) f32.
// plaq[b,h,i,j] = t0[i][j] + t1[(i+1)%64][j] - t0[i][(j+1)%64] - t1[i][j]
// out[b,h] = mean_{i,j} cos(plaq)
//
// float4 version: lane L handles row dr=L>>4 of a 4-row group, cols
// 4c..4c+3 (c=L&15).  Wave w owns rows 16w..16w+15 in 4 iterations.
// Row-neighbor t1[i+1][j] comes from a redundant float4 load at +1 row
// (same cache lines as t1[i] of this/next iter -> L2/MSHR merge, no
// extra HBM traffic -- verified: register-pipelined variant that
// eliminates the duplicate load benches identical, R1).
// Col-neighbor t0[i][j+1]: in-register (.y/.z/.w) except the float4
// boundary, which is one ds_bpermute of the next lane's .x.
//
// Bottleneck accounting (R0/R1 rocprof): total = 2 harness re-poison
// fills (2 x 77 us @ 86-87% HBM peak, fixed) + kernel ~29 us vs a
// 21.3 us pure-read floor (134 MB @ 6.3 TB/s) + launch/graph overhead.
// Memory-roofline-bound; VALU est. ~2 us.

__global__ __launch_bounds__(256) void plaq_mean_cos_kernel(
    const float* __restrict__ x, float* __restrict__ out) {
    const int t    = threadIdx.x;
    const int lane = t & 63;
    const int w    = t >> 6;            // wave: rows 16w..16w+15
    const int dr   = lane >> 4;         // row-in-group 0..3
    const int c    = lane & 15;         // col group: cols 4c..4c+3
    const int bh   = blockIdx.x;

    const float* __restrict__ base = x + (size_t)bh * 8192;  // [2][64][64]
    const float* __restrict__ t0p  = base;
    const float* __restrict__ t1p  = base + 4096;

    // lane index for the col-neighbor's .x: same dr, col group c+1 (mod 16)
    const int nlane = (lane & 48) | ((c + 1) & 15);

    float sum = 0.0f;
    #pragma unroll
    for (int k = 0; k < 4; ++k) {
        const int i   = (w << 4) + (k << 2) + dr;   // this lane's row
        const int inx = (i + 1) & 63;               // row neighbor (wraps)
        const int off = (i << 6) + (c << 2);
        const float4 t0v = *(const float4*)&t0p[off];
        const float4 t1v = *(const float4*)&t1p[off];
        const float4 t1n = *(const float4*)&t1p[(inx << 6) + (c << 2)];
        const float  nx  = __shfl(t0v.x, nlane, 64);  // t0[i][4(c+1)]

        sum += __cosf(t0v.x + t1n.x - t0v.y - t1v.x);
        sum += __cosf(t0v.y + t1n.y - t0v.z - t1v.y);
        sum += __cosf(t0v.z + t1n.z - t0v.w - t1v.z);
        sum += __cosf(t0v.w + t1n.w - nx    - t1v.w);
    }

    // Wave (64-lane) butterfly reduce.
    #pragma unroll
    for (int off = 32; off > 0; off >>= 1)
        sum += __shfl_down(sum, off, 64);

    __shared__ float wsum[4];
    if (lane == 0) wsum[w] = sum;
    __syncthreads();
    if (t == 0)
        out[bh] = (wsum[0] + wsum[1] + wsum[2] + wsum[3]) * (1.0f / 4096.0f);
}

extern "C" void kernel_launch(void* const* d_in, const int* in_sizes, int n_in,
                              void* d_out, int out_size, void* d_ws, size_t ws_size,
                              hipStream_t stream) {
    const float* x = (const float*)d_in[0];
    float* out = (float*)d_out;
    plaq_mean_cos_kernel<<<4096, 256, 0, stream>>>(x, out);
}